// Round 12
// baseline (264.066 us; speedup 1.0000x reference)
//
#include <hip/hip_runtime.h>
#include <hip/hip_bf16.h>

#define HEADS 16
#define HDIM  64
#define EMB   1024
#define NB    8
#define SEQ   1024

typedef __bf16 bf16_t;
typedef __bf16 bf16x8 __attribute__((ext_vector_type(8)));
typedef __bf16 bf16x4 __attribute__((ext_vector_type(4)));
typedef float  floatx4 __attribute__((ext_vector_type(4)));
typedef float  f32x16  __attribute__((ext_vector_type(16)));
typedef unsigned uint2v __attribute__((ext_vector_type(2)));

union PkU { unsigned u; __bf16 h[2]; };
union W4U { unsigned u[4]; bf16x8 v; };

__device__ __forceinline__ bf16x8 load8bf(const bf16_t* p) { return *(const bf16x8*)p; }
__device__ __forceinline__ bf16x4 cvt4(float4 a) {
    bf16x4 r; r[0]=(bf16_t)a.x; r[1]=(bf16_t)a.y; r[2]=(bf16_t)a.z; r[3]=(bf16_t)a.w;
    return r;
}
__device__ __forceinline__ bf16x8 cvt8(float4 a, float4 b) {
    bf16x8 r;
    r[0]=(bf16_t)a.x; r[1]=(bf16_t)a.y; r[2]=(bf16_t)a.z; r[3]=(bf16_t)a.w;
    r[4]=(bf16_t)b.x; r[5]=(bf16_t)b.y; r[6]=(bf16_t)b.z; r[7]=(bf16_t)b.w;
    return r;
}

// ---------------------------------------------------------------------------
// Kernel 1: per-head projections. Round-12: GRID-STRIDE — each block now
// processes 4 consecutive tiles with W loaded ONCE (was 6144 blocks each
// reloading the same 16KB W = 24 sequential block-rounds/CU, ~3x roofline).
// lo is ping-ponged so it stays 1 barrier/tile: write lo[i&1] -> sync ->
// read/store; reuse of lo[b] at tile i+2 is ordered by the sync at i+1.
// Per-tile math/layout byte-identical to the r11 passing version (incl. the
// CE pre-scale on Q).
// ---------------------------------------------------------------------------
__global__ __launch_bounds__(256) void proj_kernel(
    const float* __restrict__ q_in, const float* __restrict__ k_in,
    const float* __restrict__ v_in,
    const float* __restrict__ Wq, const float* __restrict__ Wk,
    const float* __restrict__ Wv,
    bf16_t* __restrict__ qp, bf16_t* __restrict__ kp, bf16_t* __restrict__ vt)
{
    __shared__ __align__(16) bf16_t wl[64][72];
    __shared__ __align__(16) bf16_t lo[2][64][72];   // ping-pong output staging

    const int wave = threadIdx.x >> 6;
    const int lane = threadIdx.x & 63;
    const int m  = lane & 15;
    const int q4 = lane >> 4;
    const int op = blockIdx.y;

    const float* x = (op == 0) ? q_in : (op == 1) ? k_in : v_in;
    const float* W = (op == 0) ? Wq   : (op == 1) ? Wk   : Wv;

    {
        const int t  = threadIdx.x;
        const int f  = t >> 2;
        const int kg = (t & 3) * 16;
        #pragma unroll
        for (int j = 0; j < 4; ++j) {
            float4 v = *(const float4*)(W + f * 64 + kg + j * 4);
            *(bf16x4*)&wl[f][kg + j * 4] = cvt4(v);
        }
    }
    __syncthreads();

    #pragma unroll 1
    for (int i = 0; i < 4; ++i) {
        const int tile = blockIdx.x * 4 + i;
        const int buf  = i & 1;

        if (op == 2) {
            const int nh = tile >> 4;            // constant within block (4-aligned)
            const int l0 = (tile & 15) * 64;
            const int n  = nh >> 4;
            const int h  = nh & 15;

            const int la = l0 + wave * 16 + m;
            const float* xr = x + (size_t)(n * 16384 + la * 16 + h) * 64;
            float4 f0 = *(const float4*)(xr + q4 * 8);
            float4 f1 = *(const float4*)(xr + q4 * 8 + 4);
            float4 f2 = *(const float4*)(xr + 32 + q4 * 8);
            float4 f3 = *(const float4*)(xr + 32 + q4 * 8 + 4);
            bf16x8 a0 = cvt8(f0, f1);
            bf16x8 a1 = cvt8(f2, f3);

            floatx4 acc[4];
            #pragma unroll
            for (int sub = 0; sub < 4; ++sub) {
                bf16x8 b0 = load8bf(&wl[sub * 16 + m][q4 * 8]);
                bf16x8 b1 = load8bf(&wl[sub * 16 + m][32 + q4 * 8]);
                floatx4 z = {0.f, 0.f, 0.f, 0.f};
                z = __builtin_amdgcn_mfma_f32_16x16x32_bf16(a0, b0, z, 0, 0, 0);
                z = __builtin_amdgcn_mfma_f32_16x16x32_bf16(a1, b1, z, 0, 0, 0);
                acc[sub] = z;
            }

            #pragma unroll
            for (int sub = 0; sub < 4; ++sub) {
                #pragma unroll
                for (int r = 0; r < 4; r += 2) {
                    PkU u; u.h[0] = (bf16_t)acc[sub][r]; u.h[1] = (bf16_t)acc[sub][r + 1];
                    *(unsigned*)&lo[buf][sub * 16 + m][wave * 16 + q4 * 4 + r] = u.u;
                }
            }
            __syncthreads();

            const int e  = threadIdx.x >> 2;
            const int lc = (threadIdx.x & 3) * 16;
            bf16_t* dst = vt + ((size_t)nh * 64 + e) * 1024 + l0 + lc;
            *(bf16x8*)dst       = *(const bf16x8*)&lo[buf][e][lc];
            *(bf16x8*)(dst + 8) = *(const bf16x8*)&lo[buf][e][lc + 8];
        } else {
            const float qscale = (op == 0) ? (1.4426950408889634f * 0.03125f) : 1.0f;
            const int row0 = tile * 64 + wave * 16;

            const float* xr = x + (size_t)(row0 + m) * 64;
            float4 f0 = *(const float4*)(xr + q4 * 8);
            float4 f1 = *(const float4*)(xr + q4 * 8 + 4);
            float4 f2 = *(const float4*)(xr + 32 + q4 * 8);
            float4 f3 = *(const float4*)(xr + 32 + q4 * 8 + 4);
            bf16x8 a0 = cvt8(f0, f1);
            bf16x8 a1 = cvt8(f2, f3);

            floatx4 acc[4];
            #pragma unroll
            for (int sub = 0; sub < 4; ++sub) {
                bf16x8 b0 = load8bf(&wl[sub * 16 + m][q4 * 8]);
                bf16x8 b1 = load8bf(&wl[sub * 16 + m][32 + q4 * 8]);
                floatx4 z = {0.f, 0.f, 0.f, 0.f};
                z = __builtin_amdgcn_mfma_f32_16x16x32_bf16(a0, b0, z, 0, 0, 0);
                z = __builtin_amdgcn_mfma_f32_16x16x32_bf16(a1, b1, z, 0, 0, 0);
                acc[sub] = z;
            }

            #pragma unroll
            for (int sub = 0; sub < 4; ++sub) {
                #pragma unroll
                for (int r = 0; r < 4; ++r) {
                    lo[buf][wave * 16 + q4 * 4 + r][sub * 16 + m] = (bf16_t)(acc[sub][r] * qscale);
                }
            }
            __syncthreads();

            const int gl = threadIdx.x >> 2;
            const int ec = (threadIdx.x & 3) * 16;
            const int g  = tile * 64 + gl;
            const int n  = g >> 14;
            const int l  = (g >> 4) & 1023;
            const int h  = g & 15;
            const int nh = n * 16 + h;
            bf16_t* dst = ((op == 0) ? qp : kp) + ((size_t)nh * 1024 + l) * 64 + ec;
            *(bf16x8*)dst       = *(const bf16x8*)&lo[buf][gl][ec];
            *(bf16x8*)(dst + 8) = *(const bf16x8*)&lo[buf][gl][ec + 8];
        }
    }
}

// ---------------------------------------------------------------------------
// Kernel 2: flash attention, 32x32 swapped-QK — BYTE-IDENTICAL to the
// round-11 passing version (75.1us, VGPR 80, MfmaUtil 23.4%, validated).
// ---------------------------------------------------------------------------
__global__ __launch_bounds__(256) void attn_kernel(
    bf16_t* __restrict__ qp, const bf16_t* __restrict__ kp,
    const bf16_t* __restrict__ vt)
{
    __shared__ __align__(16) bf16_t kl[2][64][64];
    __shared__ __align__(16) bf16_t vl[2][64][64];

    const int lane = threadIdx.x & 63;
    const int wave = threadIdx.x >> 6;
    const int q32  = lane & 31;          // this lane's query column
    const int hi   = lane >> 5;          // half-wave id

    const int nh   = blockIdx.x & 127;   // same-nh blocks -> same XCD
    const int qblk = blockIdx.x >> 7;    // 0..7

    bf16_t* Q = qp + (size_t)nh * 65536;
    const bf16_t* K = kp + (size_t)nh * 65536;
    const bf16_t* V = vt + (size_t)nh * 65536;   // [D][L]

    const int qb = qblk * 128 + wave * 32;       // this wave's 32 queries

    const int srow  = lane >> 3;
    const int sslot = lane & 7;
    const int ch    = sslot ^ srow;

    auto stage = [&](int b, int kb) {
        #pragma unroll
        for (int i = 0; i < 2; ++i) {
            const int rbase = wave * 16 + i * 8;
            const int row   = rbase + srow;
            __builtin_amdgcn_global_load_lds(
                (const __attribute__((address_space(1))) unsigned int*)(K + (size_t)(kb + row) * 64 + ch * 8),
                (__attribute__((address_space(3))) unsigned int*)(&kl[b][rbase][0]),
                16, 0, 0);
            __builtin_amdgcn_global_load_lds(
                (const __attribute__((address_space(1))) unsigned int*)(V + (size_t)row * 1024 + kb + ch * 8),
                (__attribute__((address_space(3))) unsigned int*)(&vl[b][rbase][0]),
                16, 0, 0);
        }
    };

    stage(0, 0);   // prologue: tile 0 in flight

    // Q B-fragments: col q = q32, k(d) = slice*16 + hi*8 + j  (pre-scaled by CE)
    bf16x8 bq[4];
    #pragma unroll
    for (int sl = 0; sl < 4; ++sl)
        bq[sl] = load8bf(Q + (size_t)(qb + q32) * 64 + sl * 16 + hi * 8);

    // all-ones A fragment for the MFMA column-sum of P (layout-independent)
    bf16x8 ones;
    #pragma unroll
    for (int j = 0; j < 8; ++j) ones[j] = (bf16_t)1.0f;

    f32x16 o0 = {0.f,0.f,0.f,0.f,0.f,0.f,0.f,0.f,0.f,0.f,0.f,0.f,0.f,0.f,0.f,0.f};
    f32x16 o1 = o0;
    f32x16 osum = o0;

    int cur = 0;
    __syncthreads();   // drains prologue stage + barrier

    for (int kt = 0; kt < 16; ++kt) {
        if (kt < 15) stage(cur ^ 1, (kt + 1) * 64);   // next tile under compute

        #pragma unroll
        for (int kb32 = 0; kb32 < 2; ++kb32) {
            const int krow = kb32 * 32 + q32;
            f32x16 s = {0.f,0.f,0.f,0.f,0.f,0.f,0.f,0.f,0.f,0.f,0.f,0.f,0.f,0.f,0.f,0.f};
            __builtin_amdgcn_s_setprio(1);
            #pragma unroll
            for (int sl = 0; sl < 4; ++sl) {
                const int ck = ((sl * 2 + hi) ^ (krow & 7)) * 8;
                bf16x8 ka = load8bf(&kl[cur][krow][ck]);
                s = __builtin_amdgcn_mfma_f32_32x32x16_bf16(ka, bq[sl], s, 0, 0, 0);
            }
            __builtin_amdgcn_s_setprio(0);

            // p = exp2(s) (CE pre-folded); pack pairs to bf16x2 words
            unsigned w[8];
            #pragma unroll
            for (int t = 0; t < 8; ++t) {
                float p0 = exp2f(s[2 * t]);
                float p1 = exp2f(s[2 * t + 1]);
                PkU u; u.h[0] = (bf16_t)p0; u.h[1] = (bf16_t)p1;
                w[t] = u.u;
            }

            // V fragments issued early (hide ds latency under the swaps)
            bf16x8 va[4];
            #pragma unroll
            for (int db = 0; db < 2; ++db) {
                const int d = db * 32 + q32;
                #pragma unroll
                for (int c = 0; c < 2; ++c) {
                    const int cv = ((kb32 * 4 + c * 2 + hi) ^ (d & 7)) * 8;
                    va[db * 2 + c] = load8bf(&vl[cur][d][cv]);
                }
            }

            // half-exchange via permlane32_swap: ret0={a.lo,b.lo}, ret1={a.hi,b.hi}
            W4U b0v, b1v;
            uint2v r02 = __builtin_amdgcn_permlane32_swap(w[0], w[2], false, false);
            b0v.u[0] = r02[0]; b0v.u[2] = r02[1];
            uint2v r13 = __builtin_amdgcn_permlane32_swap(w[1], w[3], false, false);
            b0v.u[1] = r13[0]; b0v.u[3] = r13[1];
            uint2v r46 = __builtin_amdgcn_permlane32_swap(w[4], w[6], false, false);
            b1v.u[0] = r46[0]; b1v.u[2] = r46[1];
            uint2v r57 = __builtin_amdgcn_permlane32_swap(w[5], w[7], false, false);
            b1v.u[1] = r57[0]; b1v.u[3] = r57[1];

            // O^T[d][q] += V^T-frag x P-frag; osum accumulates colsum(P)
            __builtin_amdgcn_s_setprio(1);
            o0 = __builtin_amdgcn_mfma_f32_32x32x16_bf16(va[0], b0v.v, o0, 0, 0, 0);
            o0 = __builtin_amdgcn_mfma_f32_32x32x16_bf16(va[1], b1v.v, o0, 0, 0, 0);
            o1 = __builtin_amdgcn_mfma_f32_32x32x16_bf16(va[2], b0v.v, o1, 0, 0, 0);
            o1 = __builtin_amdgcn_mfma_f32_32x32x16_bf16(va[3], b1v.v, o1, 0, 0, 0);
            osum = __builtin_amdgcn_mfma_f32_32x32x16_bf16(ones, b0v.v, osum, 0, 0, 0);
            osum = __builtin_amdgcn_mfma_f32_32x32x16_bf16(ones, b1v.v, osum, 0, 0, 0);
            __builtin_amdgcn_s_setprio(0);
        }

        __syncthreads();
        cur ^= 1;
    }

    // all rows of osum are identical colsums of P -> reg 0 holds l for q=q32
    const float inv = 1.0f / osum[0];

    #pragma unroll
    for (int g = 0; g < 4; ++g) {
        bf16x4 w0v, w1v;
        #pragma unroll
        for (int r = 0; r < 4; ++r) {
            w0v[r] = (bf16_t)(o0[g * 4 + r] * inv);
            w1v[r] = (bf16_t)(o1[g * 4 + r] * inv);
        }
        *(bf16x4*)(Q + (size_t)(qb + q32) * 64 +      g * 8 + hi * 4) = w0v;
        *(bf16x4*)(Q + (size_t)(qb + q32) * 64 + 32 + g * 8 + hi * 4) = w1v;
    }
}

// ---------------------------------------------------------------------------
// Kernel 3: out(fp32) = AO @ Wo^T. Round-12: identical structure to the r10
// passing version (128x64 tiles, grid 1024, 2-barrier LDS staging), but the
// staging loads fp32 Wo and converts inline -> the wocvt kernel (and its
// dispatch gap) is deleted. Extra staged bytes come from the 256KB
// L2-resident per-XCD Wo slice. Same fp32->bf16 rounding as wocvt.
// ---------------------------------------------------------------------------
__global__ __launch_bounds__(256) void outproj_kernel(
    const bf16_t* __restrict__ aoq, const float* __restrict__ Wo,
    float* __restrict__ out)
{
    __shared__ __align__(16) bf16_t wl[64][72];

    const int wave = threadIdx.x >> 6;
    const int lane = threadIdx.x & 63;
    const int m  = lane & 15;
    const int q4 = lane >> 4;

    const int by = blockIdx.x & 15;      // col-block 0..15
    const int bx = blockIdx.x >> 4;      // row-block 0..63

    const int row0 = bx * 128 + wave * 32;   // this wave's 32 rows
    const int col0 = by * 64;

    const int ts_f  = threadIdx.x >> 2;         // Wo col within tile 0..63
    const int ts_kg = (threadIdx.x & 3) * 16;   // 16-elem k chunk

    floatx4 acc[2][4];
    #pragma unroll
    for (int rs = 0; rs < 2; ++rs)
        #pragma unroll
        for (int cs = 0; cs < 4; ++cs) acc[rs][cs] = (floatx4){0.f, 0.f, 0.f, 0.f};

    for (int h = 0; h < 16; ++h) {
        const int kc = h * 64;
        __syncthreads();
        {
            const float* wrow = Wo + (size_t)(col0 + ts_f) * 1024 + kc + ts_kg;
            float4 w0 = *(const float4*)(wrow);
            float4 w1 = *(const float4*)(wrow + 4);
            float4 w2 = *(const float4*)(wrow + 8);
            float4 w3 = *(const float4*)(wrow + 12);
            *(bf16x8*)&wl[ts_f][ts_kg]     = cvt8(w0, w1);
            *(bf16x8*)&wl[ts_f][ts_kg + 8] = cvt8(w2, w3);
        }
        __syncthreads();

        bf16x8 a[2][2];
        #pragma unroll
        for (int rs = 0; rs < 2; ++rs) {
            const int g = row0 + rs * 16 + m;
            const int n = g >> 10;
            const int q = g & 1023;
            const bf16_t* arow = aoq + ((size_t)(n * 16 + h) * 1024 + q) * 64;
            a[rs][0] = load8bf(arow + q4 * 8);
            a[rs][1] = load8bf(arow + 32 + q4 * 8);
        }

        #pragma unroll
        for (int cs = 0; cs < 4; ++cs) {
            bf16x8 b0 = load8bf(&wl[cs * 16 + m][q4 * 8]);
            bf16x8 b1 = load8bf(&wl[cs * 16 + m][32 + q4 * 8]);
            #pragma unroll
            for (int rs = 0; rs < 2; ++rs) {
                acc[rs][cs] = __builtin_amdgcn_mfma_f32_16x16x32_bf16(a[rs][0], b0, acc[rs][cs], 0, 0, 0);
                acc[rs][cs] = __builtin_amdgcn_mfma_f32_16x16x32_bf16(a[rs][1], b1, acc[rs][cs], 0, 0, 0);
            }
        }
    }

    #pragma unroll
    for (int rs = 0; rs < 2; ++rs) {
        #pragma unroll
        for (int r = 0; r < 4; ++r) {
            const int g = row0 + rs * 16 + q4 * 4 + r;
            #pragma unroll
            for (int cs = 0; cs < 4; ++cs)
                out[(size_t)g * 1024 + col0 + cs * 16 + m] = acc[rs][cs][r];
        }
    }
}

// ---------------------------------------------------------------------------
extern "C" void kernel_launch(void* const* d_in, const int* in_sizes, int n_in,
                              void* d_out, int out_size, void* d_ws, size_t ws_size,
                              hipStream_t stream) {
    const float* key   = (const float*)d_in[0];
    const float* query = (const float*)d_in[1];
    const float* value = (const float*)d_in[2];
    // d_in[3] = mask — faithfully ignored per the reference
    const float* Wq = (const float*)d_in[4];
    const float* Wk = (const float*)d_in[5];
    const float* Wv = (const float*)d_in[6];
    const float* Wo = (const float*)d_in[7];

    const size_t TENS = (size_t)NB * SEQ * EMB;   // 8388608
    bf16_t* qp = (bf16_t*)d_ws;                   // [N*H][L][D]; becomes AO in-place
    bf16_t* vt = qp + TENS;                       // [N*H][D][L]
    bf16_t* kp = (bf16_t*)d_out;                  // staged in d_out, dead before outproj

    hipLaunchKernelGGL(proj_kernel, dim3(512, 3), dim3(256), 0, stream,
                       query, key, value, Wq, Wk, Wv, qp, kp, vt);
    hipLaunchKernelGGL(attn_kernel, dim3(1024), dim3(256), 0, stream, qp, kp, vt);
    hipLaunchKernelGGL(outproj_kernel, dim3(1024), dim3(256), 0, stream,
                       qp, Wo, (float*)d_out);
}

// Round 13
// 257.145 us; speedup vs baseline: 1.0269x; 1.0269x over previous
//
#include <hip/hip_runtime.h>
#include <hip/hip_bf16.h>

#define HEADS 16
#define HDIM  64
#define EMB   1024
#define NB    8
#define SEQ   1024

typedef __bf16 bf16_t;
typedef __bf16 bf16x8 __attribute__((ext_vector_type(8)));
typedef __bf16 bf16x4 __attribute__((ext_vector_type(4)));
typedef float  floatx4 __attribute__((ext_vector_type(4)));
typedef float  f32x16  __attribute__((ext_vector_type(16)));
typedef unsigned uint2v __attribute__((ext_vector_type(2)));

union PkU { unsigned u; __bf16 h[2]; };
union W4U { unsigned u[4]; bf16x8 v; };

__device__ __forceinline__ bf16x8 load8bf(const bf16_t* p) { return *(const bf16x8*)p; }
__device__ __forceinline__ bf16x4 cvt4(float4 a) {
    bf16x4 r; r[0]=(bf16_t)a.x; r[1]=(bf16_t)a.y; r[2]=(bf16_t)a.z; r[3]=(bf16_t)a.w;
    return r;
}
__device__ __forceinline__ bf16x8 cvt8(float4 a, float4 b) {
    bf16x8 r;
    r[0]=(bf16_t)a.x; r[1]=(bf16_t)a.y; r[2]=(bf16_t)a.z; r[3]=(bf16_t)a.w;
    r[4]=(bf16_t)b.x; r[5]=(bf16_t)b.y; r[6]=(bf16_t)b.z; r[7]=(bf16_t)b.w;
    return r;
}

// ---------------------------------------------------------------------------
// Kernel 1: per-head projections — byte-identical to the ROUND-11 passing
// version (grid 2048x3, CE pre-scale on Q). r12's grid-stride variant
// regressed (serialization outweighed W-reuse) and is reverted.
// ---------------------------------------------------------------------------
__global__ __launch_bounds__(256) void proj_kernel(
    const float* __restrict__ q_in, const float* __restrict__ k_in,
    const float* __restrict__ v_in,
    const float* __restrict__ Wq, const float* __restrict__ Wk,
    const float* __restrict__ Wv,
    bf16_t* __restrict__ qp, bf16_t* __restrict__ kp, bf16_t* __restrict__ vt)
{
    __shared__ __align__(16) bf16_t wl[64][72];
    __shared__ __align__(16) bf16_t lo[64][72];   // output staging

    const int wave = threadIdx.x >> 6;
    const int lane = threadIdx.x & 63;
    const int m  = lane & 15;
    const int q4 = lane >> 4;
    const int op = blockIdx.y;

    const float* x = (op == 0) ? q_in : (op == 1) ? k_in : v_in;
    const float* W = (op == 0) ? Wq   : (op == 1) ? Wk   : Wv;

    {
        const int t  = threadIdx.x;
        const int f  = t >> 2;
        const int kg = (t & 3) * 16;
        #pragma unroll
        for (int j = 0; j < 4; ++j) {
            float4 v = *(const float4*)(W + f * 64 + kg + j * 4);
            *(bf16x4*)&wl[f][kg + j * 4] = cvt4(v);
        }
    }
    __syncthreads();

    if (op == 2) {
        const int nh = blockIdx.x >> 4;          // 0..127
        const int l0 = (blockIdx.x & 15) * 64;
        const int n  = nh >> 4;
        const int h  = nh & 15;

        const int la = l0 + wave * 16 + m;
        const float* xr = x + (size_t)(n * 16384 + la * 16 + h) * 64;
        float4 f0 = *(const float4*)(xr + q4 * 8);
        float4 f1 = *(const float4*)(xr + q4 * 8 + 4);
        float4 f2 = *(const float4*)(xr + 32 + q4 * 8);
        float4 f3 = *(const float4*)(xr + 32 + q4 * 8 + 4);
        bf16x8 a0 = cvt8(f0, f1);
        bf16x8 a1 = cvt8(f2, f3);

        floatx4 acc[4];
        #pragma unroll
        for (int sub = 0; sub < 4; ++sub) {
            bf16x8 b0 = load8bf(&wl[sub * 16 + m][q4 * 8]);
            bf16x8 b1 = load8bf(&wl[sub * 16 + m][32 + q4 * 8]);
            floatx4 z = {0.f, 0.f, 0.f, 0.f};
            z = __builtin_amdgcn_mfma_f32_16x16x32_bf16(a0, b0, z, 0, 0, 0);
            z = __builtin_amdgcn_mfma_f32_16x16x32_bf16(a1, b1, z, 0, 0, 0);
            acc[sub] = z;
        }

        #pragma unroll
        for (int sub = 0; sub < 4; ++sub) {
            #pragma unroll
            for (int r = 0; r < 4; r += 2) {
                PkU u; u.h[0] = (bf16_t)acc[sub][r]; u.h[1] = (bf16_t)acc[sub][r + 1];
                *(unsigned*)&lo[sub * 16 + m][wave * 16 + q4 * 4 + r] = u.u;
            }
        }
        __syncthreads();

        const int e  = threadIdx.x >> 2;
        const int lc = (threadIdx.x & 3) * 16;
        bf16_t* dst = vt + ((size_t)nh * 64 + e) * 1024 + l0 + lc;
        *(bf16x8*)dst       = *(const bf16x8*)&lo[e][lc];
        *(bf16x8*)(dst + 8) = *(const bf16x8*)&lo[e][lc + 8];
    } else {
        const float qscale = (op == 0) ? (1.4426950408889634f * 0.03125f) : 1.0f;
        const int row0 = blockIdx.x * 64 + wave * 16;

        const float* xr = x + (size_t)(row0 + m) * 64;
        float4 f0 = *(const float4*)(xr + q4 * 8);
        float4 f1 = *(const float4*)(xr + q4 * 8 + 4);
        float4 f2 = *(const float4*)(xr + 32 + q4 * 8);
        float4 f3 = *(const float4*)(xr + 32 + q4 * 8 + 4);
        bf16x8 a0 = cvt8(f0, f1);
        bf16x8 a1 = cvt8(f2, f3);

        floatx4 acc[4];
        #pragma unroll
        for (int sub = 0; sub < 4; ++sub) {
            bf16x8 b0 = load8bf(&wl[sub * 16 + m][q4 * 8]);
            bf16x8 b1 = load8bf(&wl[sub * 16 + m][32 + q4 * 8]);
            floatx4 z = {0.f, 0.f, 0.f, 0.f};
            z = __builtin_amdgcn_mfma_f32_16x16x32_bf16(a0, b0, z, 0, 0, 0);
            z = __builtin_amdgcn_mfma_f32_16x16x32_bf16(a1, b1, z, 0, 0, 0);
            acc[sub] = z;
        }

        // stage tile in natural [g_local][e] layout (Q pre-scaled by CE)
        #pragma unroll
        for (int sub = 0; sub < 4; ++sub) {
            #pragma unroll
            for (int r = 0; r < 4; ++r) {
                lo[wave * 16 + q4 * 4 + r][sub * 16 + m] = (bf16_t)(acc[sub][r] * qscale);
            }
        }
        __syncthreads();

        const int gl = threadIdx.x >> 2;
        const int ec = (threadIdx.x & 3) * 16;
        const int g  = blockIdx.x * 64 + gl;
        const int n  = g >> 14;
        const int l  = (g >> 4) & 1023;
        const int h  = g & 15;
        const int nh = n * 16 + h;
        bf16_t* dst = ((op == 0) ? qp : kp) + ((size_t)nh * 1024 + l) * 64 + ec;
        *(bf16x8*)dst       = *(const bf16x8*)&lo[gl][ec];
        *(bf16x8*)(dst + 8) = *(const bf16x8*)&lo[gl][ec + 8];
    }
}

// ---------------------------------------------------------------------------
// Kernel 2: flash attention, 32x32 swapped-QK — BYTE-IDENTICAL to the
// round-11 passing version (75.1us, VGPR 80, MfmaUtil 23.4%, validated).
// ---------------------------------------------------------------------------
__global__ __launch_bounds__(256) void attn_kernel(
    bf16_t* __restrict__ qp, const bf16_t* __restrict__ kp,
    const bf16_t* __restrict__ vt)
{
    __shared__ __align__(16) bf16_t kl[2][64][64];
    __shared__ __align__(16) bf16_t vl[2][64][64];

    const int lane = threadIdx.x & 63;
    const int wave = threadIdx.x >> 6;
    const int q32  = lane & 31;          // this lane's query column
    const int hi   = lane >> 5;          // half-wave id

    const int nh   = blockIdx.x & 127;   // same-nh blocks -> same XCD
    const int qblk = blockIdx.x >> 7;    // 0..7

    bf16_t* Q = qp + (size_t)nh * 65536;
    const bf16_t* K = kp + (size_t)nh * 65536;
    const bf16_t* V = vt + (size_t)nh * 65536;   // [D][L]

    const int qb = qblk * 128 + wave * 32;       // this wave's 32 queries

    const int srow  = lane >> 3;
    const int sslot = lane & 7;
    const int ch    = sslot ^ srow;

    auto stage = [&](int b, int kb) {
        #pragma unroll
        for (int i = 0; i < 2; ++i) {
            const int rbase = wave * 16 + i * 8;
            const int row   = rbase + srow;
            __builtin_amdgcn_global_load_lds(
                (const __attribute__((address_space(1))) unsigned int*)(K + (size_t)(kb + row) * 64 + ch * 8),
                (__attribute__((address_space(3))) unsigned int*)(&kl[b][rbase][0]),
                16, 0, 0);
            __builtin_amdgcn_global_load_lds(
                (const __attribute__((address_space(1))) unsigned int*)(V + (size_t)row * 1024 + kb + ch * 8),
                (__attribute__((address_space(3))) unsigned int*)(&vl[b][rbase][0]),
                16, 0, 0);
        }
    };

    stage(0, 0);   // prologue: tile 0 in flight

    // Q B-fragments: col q = q32, k(d) = slice*16 + hi*8 + j  (pre-scaled by CE)
    bf16x8 bq[4];
    #pragma unroll
    for (int sl = 0; sl < 4; ++sl)
        bq[sl] = load8bf(Q + (size_t)(qb + q32) * 64 + sl * 16 + hi * 8);

    // all-ones A fragment for the MFMA column-sum of P (layout-independent)
    bf16x8 ones;
    #pragma unroll
    for (int j = 0; j < 8; ++j) ones[j] = (bf16_t)1.0f;

    f32x16 o0 = {0.f,0.f,0.f,0.f,0.f,0.f,0.f,0.f,0.f,0.f,0.f,0.f,0.f,0.f,0.f,0.f};
    f32x16 o1 = o0;
    f32x16 osum = o0;

    int cur = 0;
    __syncthreads();   // drains prologue stage + barrier

    for (int kt = 0; kt < 16; ++kt) {
        if (kt < 15) stage(cur ^ 1, (kt + 1) * 64);   // next tile under compute

        #pragma unroll
        for (int kb32 = 0; kb32 < 2; ++kb32) {
            const int krow = kb32 * 32 + q32;
            f32x16 s = {0.f,0.f,0.f,0.f,0.f,0.f,0.f,0.f,0.f,0.f,0.f,0.f,0.f,0.f,0.f,0.f};
            __builtin_amdgcn_s_setprio(1);
            #pragma unroll
            for (int sl = 0; sl < 4; ++sl) {
                const int ck = ((sl * 2 + hi) ^ (krow & 7)) * 8;
                bf16x8 ka = load8bf(&kl[cur][krow][ck]);
                s = __builtin_amdgcn_mfma_f32_32x32x16_bf16(ka, bq[sl], s, 0, 0, 0);
            }
            __builtin_amdgcn_s_setprio(0);

            // p = exp2(s) (CE pre-folded); pack pairs to bf16x2 words
            unsigned w[8];
            #pragma unroll
            for (int t = 0; t < 8; ++t) {
                float p0 = exp2f(s[2 * t]);
                float p1 = exp2f(s[2 * t + 1]);
                PkU u; u.h[0] = (bf16_t)p0; u.h[1] = (bf16_t)p1;
                w[t] = u.u;
            }

            // V fragments issued early (hide ds latency under the swaps)
            bf16x8 va[4];
            #pragma unroll
            for (int db = 0; db < 2; ++db) {
                const int d = db * 32 + q32;
                #pragma unroll
                for (int c = 0; c < 2; ++c) {
                    const int cv = ((kb32 * 4 + c * 2 + hi) ^ (d & 7)) * 8;
                    va[db * 2 + c] = load8bf(&vl[cur][d][cv]);
                }
            }

            // half-exchange via permlane32_swap: ret0={a.lo,b.lo}, ret1={a.hi,b.hi}
            W4U b0v, b1v;
            uint2v r02 = __builtin_amdgcn_permlane32_swap(w[0], w[2], false, false);
            b0v.u[0] = r02[0]; b0v.u[2] = r02[1];
            uint2v r13 = __builtin_amdgcn_permlane32_swap(w[1], w[3], false, false);
            b0v.u[1] = r13[0]; b0v.u[3] = r13[1];
            uint2v r46 = __builtin_amdgcn_permlane32_swap(w[4], w[6], false, false);
            b1v.u[0] = r46[0]; b1v.u[2] = r46[1];
            uint2v r57 = __builtin_amdgcn_permlane32_swap(w[5], w[7], false, false);
            b1v.u[1] = r57[0]; b1v.u[3] = r57[1];

            // O^T[d][q] += V^T-frag x P-frag; osum accumulates colsum(P)
            __builtin_amdgcn_s_setprio(1);
            o0 = __builtin_amdgcn_mfma_f32_32x32x16_bf16(va[0], b0v.v, o0, 0, 0, 0);
            o0 = __builtin_amdgcn_mfma_f32_32x32x16_bf16(va[1], b1v.v, o0, 0, 0, 0);
            o1 = __builtin_amdgcn_mfma_f32_32x32x16_bf16(va[2], b0v.v, o1, 0, 0, 0);
            o1 = __builtin_amdgcn_mfma_f32_32x32x16_bf16(va[3], b1v.v, o1, 0, 0, 0);
            osum = __builtin_amdgcn_mfma_f32_32x32x16_bf16(ones, b0v.v, osum, 0, 0, 0);
            osum = __builtin_amdgcn_mfma_f32_32x32x16_bf16(ones, b1v.v, osum, 0, 0, 0);
            __builtin_amdgcn_s_setprio(0);
        }

        __syncthreads();
        cur ^= 1;
    }

    // all rows of osum are identical colsums of P -> reg 0 holds l for q=q32
    const float inv = 1.0f / osum[0];

    #pragma unroll
    for (int g = 0; g < 4; ++g) {
        bf16x4 w0v, w1v;
        #pragma unroll
        for (int r = 0; r < 4; ++r) {
            w0v[r] = (bf16_t)(o0[g * 4 + r] * inv);
            w1v[r] = (bf16_t)(o1[g * 4 + r] * inv);
        }
        *(bf16x4*)(Q + (size_t)(qb + q32) * 64 +      g * 8 + hi * 4) = w0v;
        *(bf16x4*)(Q + (size_t)(qb + q32) * 64 + 32 + g * 8 + hi * 4) = w1v;
    }
}

// ---------------------------------------------------------------------------
// Kernel 3a: one-shot Wo fp32 -> bf16 (into the dead vt region; validated).
// ---------------------------------------------------------------------------
__global__ __launch_bounds__(256) void wocvt_kernel(
    const float* __restrict__ Wo, bf16_t* __restrict__ wo_bf)
{
    const int i = (blockIdx.x * 256 + threadIdx.x) * 8;
    float4 f0 = *(const float4*)(Wo + i);
    float4 f1 = *(const float4*)(Wo + i + 4);
    *(bf16x8*)(wo_bf + i) = cvt8(f0, f1);
}

// ---------------------------------------------------------------------------
// Kernel 3b: out(fp32) = AO @ Wo^T. Round-13: same 128x64 tiles / grid 1024
// as r10/r11, but Wo staging now uses the ATTN-PROVEN global_load_lds
// double-buffer: prologue stage, stage h+1 before compute of h, ONE barrier
// per h-iter (was 2 + serial load->cvt->ds_write). A-fragment loads are
// issued BEFORE the stage so the compiler waits vmcnt(2) for A while the
// stage stays in flight (r8's poisoning was the reverse order). Source
// pre-swizzled ch = sslot^srow; reads use attn's verified (q4^(m&7)) pair.
// ---------------------------------------------------------------------------
__global__ __launch_bounds__(256) void outproj_kernel(
    const bf16_t* __restrict__ aoq, const bf16_t* __restrict__ wo_bf,
    float* __restrict__ out)
{
    __shared__ __align__(16) bf16_t wl[2][64][64];

    const int wave = threadIdx.x >> 6;
    const int lane = threadIdx.x & 63;
    const int m  = lane & 15;
    const int q4 = lane >> 4;

    const int by = blockIdx.x & 15;      // col-block 0..15
    const int bx = blockIdx.x >> 4;      // row-block 0..63

    const int row0 = bx * 128 + wave * 32;   // this wave's 32 rows
    const int col0 = by * 64;

    const int srow  = lane >> 3;         // 0..7
    const int sslot = lane & 7;          // 0..7
    const int ch    = sslot ^ srow;      // pre-swizzled source chunk

    auto stage = [&](int b, int h) {
        #pragma unroll
        for (int i = 0; i < 2; ++i) {
            const int rbase = wave * 16 + i * 8;
            const int row   = rbase + srow;
            __builtin_amdgcn_global_load_lds(
                (const __attribute__((address_space(1))) unsigned int*)(wo_bf + (size_t)(col0 + row) * 1024 + h * 64 + ch * 8),
                (__attribute__((address_space(3))) unsigned int*)(&wl[b][rbase][0]),
                16, 0, 0);
        }
    };

    // per-lane swizzled fragment chunk offsets (elements) — attn-verified pair
    const int c0 = (q4 ^ (m & 7)) * 8;
    const int c1 = ((q4 + 4) ^ (m & 7)) * 8;

    stage(0, 0);   // prologue: h=0 tile in flight

    floatx4 acc[2][4];
    #pragma unroll
    for (int rs = 0; rs < 2; ++rs)
        #pragma unroll
        for (int cs = 0; cs < 4; ++cs) acc[rs][cs] = (floatx4){0.f, 0.f, 0.f, 0.f};

    int cur = 0;
    __syncthreads();   // drains prologue stage + barrier

    for (int h = 0; h < 16; ++h) {
        // A-fragments FIRST (so MFMA waits vmcnt(2), stage stays in flight)
        bf16x8 a[2][2];
        #pragma unroll
        for (int rs = 0; rs < 2; ++rs) {
            const int g = row0 + rs * 16 + m;
            const int n = g >> 10;
            const int q = g & 1023;
            const bf16_t* arow = aoq + ((size_t)(n * 16 + h) * 1024 + q) * 64;
            a[rs][0] = load8bf(arow + q4 * 8);
            a[rs][1] = load8bf(arow + 32 + q4 * 8);
        }

        if (h < 15) stage(cur ^ 1, h + 1);   // next Wo tile under this compute

        #pragma unroll
        for (int cs = 0; cs < 4; ++cs) {
            const int rr = cs * 16 + m;
            bf16x8 b0 = load8bf(&wl[cur][rr][c0]);
            bf16x8 b1 = load8bf(&wl[cur][rr][c1]);
            #pragma unroll
            for (int rs = 0; rs < 2; ++rs) {
                acc[rs][cs] = __builtin_amdgcn_mfma_f32_16x16x32_bf16(a[rs][0], b0, acc[rs][cs], 0, 0, 0);
                acc[rs][cs] = __builtin_amdgcn_mfma_f32_16x16x32_bf16(a[rs][1], b1, acc[rs][cs], 0, 0, 0);
            }
        }

        __syncthreads();   // stage(cur^1) complete + all reads of cur done
        cur ^= 1;
    }

    #pragma unroll
    for (int rs = 0; rs < 2; ++rs) {
        #pragma unroll
        for (int r = 0; r < 4; ++r) {
            const int g = row0 + rs * 16 + q4 * 4 + r;
            #pragma unroll
            for (int cs = 0; cs < 4; ++cs)
                out[(size_t)g * 1024 + col0 + cs * 16 + m] = acc[rs][cs][r];
        }
    }
}

// ---------------------------------------------------------------------------
extern "C" void kernel_launch(void* const* d_in, const int* in_sizes, int n_in,
                              void* d_out, int out_size, void* d_ws, size_t ws_size,
                              hipStream_t stream) {
    const float* key   = (const float*)d_in[0];
    const float* query = (const float*)d_in[1];
    const float* value = (const float*)d_in[2];
    // d_in[3] = mask — faithfully ignored per the reference
    const float* Wq = (const float*)d_in[4];
    const float* Wk = (const float*)d_in[5];
    const float* Wv = (const float*)d_in[6];
    const float* Wo = (const float*)d_in[7];

    const size_t TENS = (size_t)NB * SEQ * EMB;   // 8388608
    bf16_t* qp = (bf16_t*)d_ws;                   // [N*H][L][D]; becomes AO in-place
    bf16_t* vt = qp + TENS;                       // [N*H][D][L]; reused for wo_bf after attn
    bf16_t* kp = (bf16_t*)d_out;                  // staged in d_out, dead before outproj

    hipLaunchKernelGGL(proj_kernel, dim3(2048, 3), dim3(256), 0, stream,
                       query, key, value, Wq, Wk, Wv, qp, kp, vt);
    hipLaunchKernelGGL(attn_kernel, dim3(1024), dim3(256), 0, stream, qp, kp, vt);
    hipLaunchKernelGGL(wocvt_kernel, dim3(512), dim3(256), 0, stream, Wo, vt);
    hipLaunchKernelGGL(outproj_kernel, dim3(1024), dim3(256), 0, stream,
                       qp, vt, (float*)d_out);
}

// Round 14
// 253.331 us; speedup vs baseline: 1.0424x; 1.0151x over previous
//
#include <hip/hip_runtime.h>
#include <hip/hip_bf16.h>

#define HEADS 16
#define HDIM  64
#define EMB   1024
#define NB    8
#define SEQ   1024

typedef __bf16 bf16_t;
typedef __bf16 bf16x8 __attribute__((ext_vector_type(8)));
typedef __bf16 bf16x4 __attribute__((ext_vector_type(4)));
typedef float  floatx4 __attribute__((ext_vector_type(4)));
typedef float  f32x16  __attribute__((ext_vector_type(16)));
typedef unsigned uint2v __attribute__((ext_vector_type(2)));

union PkU { unsigned u; __bf16 h[2]; };
union W4U { unsigned u[4]; bf16x8 v; };

__device__ __forceinline__ bf16x8 load8bf(const bf16_t* p) { return *(const bf16x8*)p; }
__device__ __forceinline__ bf16x4 cvt4(float4 a) {
    bf16x4 r; r[0]=(bf16_t)a.x; r[1]=(bf16_t)a.y; r[2]=(bf16_t)a.z; r[3]=(bf16_t)a.w;
    return r;
}
__device__ __forceinline__ bf16x8 cvt8(float4 a, float4 b) {
    bf16x8 r;
    r[0]=(bf16_t)a.x; r[1]=(bf16_t)a.y; r[2]=(bf16_t)a.z; r[3]=(bf16_t)a.w;
    r[4]=(bf16_t)b.x; r[5]=(bf16_t)b.y; r[6]=(bf16_t)b.z; r[7]=(bf16_t)b.w;
    return r;
}

// ---------------------------------------------------------------------------
// Kernel 1: per-head projections — r11-validated math, plus an op==3 slice
// (only when launched with grid.y==4) that performs the Wo fp32->bf16
// conversion into ws headroom, removing the separate wocvt dispatch.
// op==3 blocks early-return uniformly (no barrier hazards).
// ---------------------------------------------------------------------------
__global__ __launch_bounds__(256) void proj_kernel(
    const float* __restrict__ q_in, const float* __restrict__ k_in,
    const float* __restrict__ v_in,
    const float* __restrict__ Wq, const float* __restrict__ Wk,
    const float* __restrict__ Wv, const float* __restrict__ Wo,
    bf16_t* __restrict__ qp, bf16_t* __restrict__ kp, bf16_t* __restrict__ vt,
    bf16_t* __restrict__ wo_bf)
{
    __shared__ __align__(16) bf16_t wl[64][72];
    __shared__ __align__(16) bf16_t lo[64][72];   // output staging

    const int op = blockIdx.y;

    if (op == 3) {   // fused wocvt slice (bit-identical math to wocvt_kernel)
        if (blockIdx.x < 512) {
            const int i = (blockIdx.x * 256 + threadIdx.x) * 8;
            float4 f0 = *(const float4*)(Wo + i);
            float4 f1 = *(const float4*)(Wo + i + 4);
            *(bf16x8*)(wo_bf + i) = cvt8(f0, f1);
        }
        return;
    }

    const int wave = threadIdx.x >> 6;
    const int lane = threadIdx.x & 63;
    const int m  = lane & 15;
    const int q4 = lane >> 4;

    const float* x = (op == 0) ? q_in : (op == 1) ? k_in : v_in;
    const float* W = (op == 0) ? Wq   : (op == 1) ? Wk   : Wv;

    {
        const int t  = threadIdx.x;
        const int f  = t >> 2;
        const int kg = (t & 3) * 16;
        #pragma unroll
        for (int j = 0; j < 4; ++j) {
            float4 v = *(const float4*)(W + f * 64 + kg + j * 4);
            *(bf16x4*)&wl[f][kg + j * 4] = cvt4(v);
        }
    }
    __syncthreads();

    if (op == 2) {
        const int nh = blockIdx.x >> 4;          // 0..127
        const int l0 = (blockIdx.x & 15) * 64;
        const int n  = nh >> 4;
        const int h  = nh & 15;

        const int la = l0 + wave * 16 + m;
        const float* xr = x + (size_t)(n * 16384 + la * 16 + h) * 64;
        float4 f0 = *(const float4*)(xr + q4 * 8);
        float4 f1 = *(const float4*)(xr + q4 * 8 + 4);
        float4 f2 = *(const float4*)(xr + 32 + q4 * 8);
        float4 f3 = *(const float4*)(xr + 32 + q4 * 8 + 4);
        bf16x8 a0 = cvt8(f0, f1);
        bf16x8 a1 = cvt8(f2, f3);

        floatx4 acc[4];
        #pragma unroll
        for (int sub = 0; sub < 4; ++sub) {
            bf16x8 b0 = load8bf(&wl[sub * 16 + m][q4 * 8]);
            bf16x8 b1 = load8bf(&wl[sub * 16 + m][32 + q4 * 8]);
            floatx4 z = {0.f, 0.f, 0.f, 0.f};
            z = __builtin_amdgcn_mfma_f32_16x16x32_bf16(a0, b0, z, 0, 0, 0);
            z = __builtin_amdgcn_mfma_f32_16x16x32_bf16(a1, b1, z, 0, 0, 0);
            acc[sub] = z;
        }

        #pragma unroll
        for (int sub = 0; sub < 4; ++sub) {
            #pragma unroll
            for (int r = 0; r < 4; r += 2) {
                PkU u; u.h[0] = (bf16_t)acc[sub][r]; u.h[1] = (bf16_t)acc[sub][r + 1];
                *(unsigned*)&lo[sub * 16 + m][wave * 16 + q4 * 4 + r] = u.u;
            }
        }
        __syncthreads();

        const int e  = threadIdx.x >> 2;
        const int lc = (threadIdx.x & 3) * 16;
        bf16_t* dst = vt + ((size_t)nh * 64 + e) * 1024 + l0 + lc;
        *(bf16x8*)dst       = *(const bf16x8*)&lo[e][lc];
        *(bf16x8*)(dst + 8) = *(const bf16x8*)&lo[e][lc + 8];
    } else {
        const float qscale = (op == 0) ? (1.4426950408889634f * 0.03125f) : 1.0f;
        const int row0 = blockIdx.x * 64 + wave * 16;

        const float* xr = x + (size_t)(row0 + m) * 64;
        float4 f0 = *(const float4*)(xr + q4 * 8);
        float4 f1 = *(const float4*)(xr + q4 * 8 + 4);
        float4 f2 = *(const float4*)(xr + 32 + q4 * 8);
        float4 f3 = *(const float4*)(xr + 32 + q4 * 8 + 4);
        bf16x8 a0 = cvt8(f0, f1);
        bf16x8 a1 = cvt8(f2, f3);

        floatx4 acc[4];
        #pragma unroll
        for (int sub = 0; sub < 4; ++sub) {
            bf16x8 b0 = load8bf(&wl[sub * 16 + m][q4 * 8]);
            bf16x8 b1 = load8bf(&wl[sub * 16 + m][32 + q4 * 8]);
            floatx4 z = {0.f, 0.f, 0.f, 0.f};
            z = __builtin_amdgcn_mfma_f32_16x16x32_bf16(a0, b0, z, 0, 0, 0);
            z = __builtin_amdgcn_mfma_f32_16x16x32_bf16(a1, b1, z, 0, 0, 0);
            acc[sub] = z;
        }

        // stage tile in natural [g_local][e] layout (Q pre-scaled by CE)
        #pragma unroll
        for (int sub = 0; sub < 4; ++sub) {
            #pragma unroll
            for (int r = 0; r < 4; ++r) {
                lo[wave * 16 + q4 * 4 + r][sub * 16 + m] = (bf16_t)(acc[sub][r] * qscale);
            }
        }
        __syncthreads();

        const int gl = threadIdx.x >> 2;
        const int ec = (threadIdx.x & 3) * 16;
        const int g  = blockIdx.x * 64 + gl;
        const int n  = g >> 14;
        const int l  = (g >> 4) & 1023;
        const int h  = g & 15;
        const int nh = n * 16 + h;
        bf16_t* dst = ((op == 0) ? qp : kp) + ((size_t)nh * 1024 + l) * 64 + ec;
        *(bf16x8*)dst       = *(const bf16x8*)&lo[gl][ec];
        *(bf16x8*)(dst + 8) = *(const bf16x8*)&lo[gl][ec + 8];
    }
}

// ---------------------------------------------------------------------------
// Kernel 2: flash attention, 32x32 swapped-QK — BYTE-IDENTICAL to the
// round-11/13 passing version (~76us, VGPR 80, MfmaUtil ~23%, validated).
// ---------------------------------------------------------------------------
__global__ __launch_bounds__(256) void attn_kernel(
    bf16_t* __restrict__ qp, const bf16_t* __restrict__ kp,
    const bf16_t* __restrict__ vt)
{
    __shared__ __align__(16) bf16_t kl[2][64][64];
    __shared__ __align__(16) bf16_t vl[2][64][64];

    const int lane = threadIdx.x & 63;
    const int wave = threadIdx.x >> 6;
    const int q32  = lane & 31;          // this lane's query column
    const int hi   = lane >> 5;          // half-wave id

    const int nh   = blockIdx.x & 127;   // same-nh blocks -> same XCD
    const int qblk = blockIdx.x >> 7;    // 0..7

    bf16_t* Q = qp + (size_t)nh * 65536;
    const bf16_t* K = kp + (size_t)nh * 65536;
    const bf16_t* V = vt + (size_t)nh * 65536;   // [D][L]

    const int qb = qblk * 128 + wave * 32;       // this wave's 32 queries

    const int srow  = lane >> 3;
    const int sslot = lane & 7;
    const int ch    = sslot ^ srow;

    auto stage = [&](int b, int kb) {
        #pragma unroll
        for (int i = 0; i < 2; ++i) {
            const int rbase = wave * 16 + i * 8;
            const int row   = rbase + srow;
            __builtin_amdgcn_global_load_lds(
                (const __attribute__((address_space(1))) unsigned int*)(K + (size_t)(kb + row) * 64 + ch * 8),
                (__attribute__((address_space(3))) unsigned int*)(&kl[b][rbase][0]),
                16, 0, 0);
            __builtin_amdgcn_global_load_lds(
                (const __attribute__((address_space(1))) unsigned int*)(V + (size_t)row * 1024 + kb + ch * 8),
                (__attribute__((address_space(3))) unsigned int*)(&vl[b][rbase][0]),
                16, 0, 0);
        }
    };

    stage(0, 0);   // prologue: tile 0 in flight

    // Q B-fragments: col q = q32, k(d) = slice*16 + hi*8 + j  (pre-scaled by CE)
    bf16x8 bq[4];
    #pragma unroll
    for (int sl = 0; sl < 4; ++sl)
        bq[sl] = load8bf(Q + (size_t)(qb + q32) * 64 + sl * 16 + hi * 8);

    // all-ones A fragment for the MFMA column-sum of P (layout-independent)
    bf16x8 ones;
    #pragma unroll
    for (int j = 0; j < 8; ++j) ones[j] = (bf16_t)1.0f;

    f32x16 o0 = {0.f,0.f,0.f,0.f,0.f,0.f,0.f,0.f,0.f,0.f,0.f,0.f,0.f,0.f,0.f,0.f};
    f32x16 o1 = o0;
    f32x16 osum = o0;

    int cur = 0;
    __syncthreads();   // drains prologue stage + barrier

    for (int kt = 0; kt < 16; ++kt) {
        if (kt < 15) stage(cur ^ 1, (kt + 1) * 64);   // next tile under compute

        #pragma unroll
        for (int kb32 = 0; kb32 < 2; ++kb32) {
            const int krow = kb32 * 32 + q32;
            f32x16 s = {0.f,0.f,0.f,0.f,0.f,0.f,0.f,0.f,0.f,0.f,0.f,0.f,0.f,0.f,0.f,0.f};
            __builtin_amdgcn_s_setprio(1);
            #pragma unroll
            for (int sl = 0; sl < 4; ++sl) {
                const int ck = ((sl * 2 + hi) ^ (krow & 7)) * 8;
                bf16x8 ka = load8bf(&kl[cur][krow][ck]);
                s = __builtin_amdgcn_mfma_f32_32x32x16_bf16(ka, bq[sl], s, 0, 0, 0);
            }
            __builtin_amdgcn_s_setprio(0);

            // p = exp2(s) (CE pre-folded); pack pairs to bf16x2 words
            unsigned w[8];
            #pragma unroll
            for (int t = 0; t < 8; ++t) {
                float p0 = exp2f(s[2 * t]);
                float p1 = exp2f(s[2 * t + 1]);
                PkU u; u.h[0] = (bf16_t)p0; u.h[1] = (bf16_t)p1;
                w[t] = u.u;
            }

            // V fragments issued early (hide ds latency under the swaps)
            bf16x8 va[4];
            #pragma unroll
            for (int db = 0; db < 2; ++db) {
                const int d = db * 32 + q32;
                #pragma unroll
                for (int c = 0; c < 2; ++c) {
                    const int cv = ((kb32 * 4 + c * 2 + hi) ^ (d & 7)) * 8;
                    va[db * 2 + c] = load8bf(&vl[cur][d][cv]);
                }
            }

            // half-exchange via permlane32_swap: ret0={a.lo,b.lo}, ret1={a.hi,b.hi}
            W4U b0v, b1v;
            uint2v r02 = __builtin_amdgcn_permlane32_swap(w[0], w[2], false, false);
            b0v.u[0] = r02[0]; b0v.u[2] = r02[1];
            uint2v r13 = __builtin_amdgcn_permlane32_swap(w[1], w[3], false, false);
            b0v.u[1] = r13[0]; b0v.u[3] = r13[1];
            uint2v r46 = __builtin_amdgcn_permlane32_swap(w[4], w[6], false, false);
            b1v.u[0] = r46[0]; b1v.u[2] = r46[1];
            uint2v r57 = __builtin_amdgcn_permlane32_swap(w[5], w[7], false, false);
            b1v.u[1] = r57[0]; b1v.u[3] = r57[1];

            // O^T[d][q] += V^T-frag x P-frag; osum accumulates colsum(P)
            __builtin_amdgcn_s_setprio(1);
            o0 = __builtin_amdgcn_mfma_f32_32x32x16_bf16(va[0], b0v.v, o0, 0, 0, 0);
            o0 = __builtin_amdgcn_mfma_f32_32x32x16_bf16(va[1], b1v.v, o0, 0, 0, 0);
            o1 = __builtin_amdgcn_mfma_f32_32x32x16_bf16(va[2], b0v.v, o1, 0, 0, 0);
            o1 = __builtin_amdgcn_mfma_f32_32x32x16_bf16(va[3], b1v.v, o1, 0, 0, 0);
            osum = __builtin_amdgcn_mfma_f32_32x32x16_bf16(ones, b0v.v, osum, 0, 0, 0);
            osum = __builtin_amdgcn_mfma_f32_32x32x16_bf16(ones, b1v.v, osum, 0, 0, 0);
            __builtin_amdgcn_s_setprio(0);
        }

        __syncthreads();
        cur ^= 1;
    }

    // all rows of osum are identical colsums of P -> reg 0 holds l for q=q32
    const float inv = 1.0f / osum[0];

    #pragma unroll
    for (int g = 0; g < 4; ++g) {
        bf16x4 w0v, w1v;
        #pragma unroll
        for (int r = 0; r < 4; ++r) {
            w0v[r] = (bf16_t)(o0[g * 4 + r] * inv);
            w1v[r] = (bf16_t)(o1[g * 4 + r] * inv);
        }
        *(bf16x4*)(Q + (size_t)(qb + q32) * 64 +      g * 8 + hi * 4) = w0v;
        *(bf16x4*)(Q + (size_t)(qb + q32) * 64 + 32 + g * 8 + hi * 4) = w1v;
    }
}

// ---------------------------------------------------------------------------
// Kernel 3a: one-shot Wo fp32 -> bf16 (fallback path only, when ws headroom
// is insufficient to fuse the convert into proj).
// ---------------------------------------------------------------------------
__global__ __launch_bounds__(256) void wocvt_kernel(
    const float* __restrict__ Wo, bf16_t* __restrict__ wo_bf)
{
    const int i = (blockIdx.x * 256 + threadIdx.x) * 8;
    float4 f0 = *(const float4*)(Wo + i);
    float4 f1 = *(const float4*)(Wo + i + 4);
    *(bf16x8*)(wo_bf + i) = cvt8(f0, f1);
}

// ---------------------------------------------------------------------------
// Kernel 3b: out(fp32) = AO @ Wo^T — BYTE-IDENTICAL to the round-13 passing
// version (gload_lds double-buffered Wo staging, 128x64 tiles, grid 1024).
// ---------------------------------------------------------------------------
__global__ __launch_bounds__(256) void outproj_kernel(
    const bf16_t* __restrict__ aoq, const bf16_t* __restrict__ wo_bf,
    float* __restrict__ out)
{
    __shared__ __align__(16) bf16_t wl[2][64][64];

    const int wave = threadIdx.x >> 6;
    const int lane = threadIdx.x & 63;
    const int m  = lane & 15;
    const int q4 = lane >> 4;

    const int by = blockIdx.x & 15;      // col-block 0..15
    const int bx = blockIdx.x >> 4;      // row-block 0..63

    const int row0 = bx * 128 + wave * 32;   // this wave's 32 rows
    const int col0 = by * 64;

    const int srow  = lane >> 3;         // 0..7
    const int sslot = lane & 7;          // 0..7
    const int ch    = sslot ^ srow;      // pre-swizzled source chunk

    auto stage = [&](int b, int h) {
        #pragma unroll
        for (int i = 0; i < 2; ++i) {
            const int rbase = wave * 16 + i * 8;
            const int row   = rbase + srow;
            __builtin_amdgcn_global_load_lds(
                (const __attribute__((address_space(1))) unsigned int*)(wo_bf + (size_t)(col0 + row) * 1024 + h * 64 + ch * 8),
                (__attribute__((address_space(3))) unsigned int*)(&wl[b][rbase][0]),
                16, 0, 0);
        }
    };

    // per-lane swizzled fragment chunk offsets (elements) — attn-verified pair
    const int c0 = (q4 ^ (m & 7)) * 8;
    const int c1 = ((q4 + 4) ^ (m & 7)) * 8;

    stage(0, 0);   // prologue: h=0 tile in flight

    floatx4 acc[2][4];
    #pragma unroll
    for (int rs = 0; rs < 2; ++rs)
        #pragma unroll
        for (int cs = 0; cs < 4; ++cs) acc[rs][cs] = (floatx4){0.f, 0.f, 0.f, 0.f};

    int cur = 0;
    __syncthreads();   // drains prologue stage + barrier

    for (int h = 0; h < 16; ++h) {
        // A-fragments FIRST (so MFMA waits vmcnt(2), stage stays in flight)
        bf16x8 a[2][2];
        #pragma unroll
        for (int rs = 0; rs < 2; ++rs) {
            const int g = row0 + rs * 16 + m;
            const int n = g >> 10;
            const int q = g & 1023;
            const bf16_t* arow = aoq + ((size_t)(n * 16 + h) * 1024 + q) * 64;
            a[rs][0] = load8bf(arow + q4 * 8);
            a[rs][1] = load8bf(arow + 32 + q4 * 8);
        }

        if (h < 15) stage(cur ^ 1, h + 1);   // next Wo tile under this compute

        #pragma unroll
        for (int cs = 0; cs < 4; ++cs) {
            const int rr = cs * 16 + m;
            bf16x8 b0 = load8bf(&wl[cur][rr][c0]);
            bf16x8 b1 = load8bf(&wl[cur][rr][c1]);
            #pragma unroll
            for (int rs = 0; rs < 2; ++rs) {
                acc[rs][cs] = __builtin_amdgcn_mfma_f32_16x16x32_bf16(a[rs][0], b0, acc[rs][cs], 0, 0, 0);
                acc[rs][cs] = __builtin_amdgcn_mfma_f32_16x16x32_bf16(a[rs][1], b1, acc[rs][cs], 0, 0, 0);
            }
        }

        __syncthreads();   // stage(cur^1) complete + all reads of cur done
        cur ^= 1;
    }

    #pragma unroll
    for (int rs = 0; rs < 2; ++rs) {
        #pragma unroll
        for (int r = 0; r < 4; ++r) {
            const int g = row0 + rs * 16 + q4 * 4 + r;
            #pragma unroll
            for (int cs = 0; cs < 4; ++cs)
                out[(size_t)g * 1024 + col0 + cs * 16 + m] = acc[rs][cs][r];
        }
    }
}

// ---------------------------------------------------------------------------
extern "C" void kernel_launch(void* const* d_in, const int* in_sizes, int n_in,
                              void* d_out, int out_size, void* d_ws, size_t ws_size,
                              hipStream_t stream) {
    const float* key   = (const float*)d_in[0];
    const float* query = (const float*)d_in[1];
    const float* value = (const float*)d_in[2];
    // d_in[3] = mask — faithfully ignored per the reference
    const float* Wq = (const float*)d_in[4];
    const float* Wk = (const float*)d_in[5];
    const float* Wv = (const float*)d_in[6];
    const float* Wo = (const float*)d_in[7];

    const size_t TENS = (size_t)NB * SEQ * EMB;   // 8388608 elements
    const size_t WO_E = (size_t)EMB * EMB;        // 1048576 elements
    bf16_t* qp = (bf16_t*)d_ws;                   // [N*H][L][D]; becomes AO in-place
    bf16_t* vt = qp + TENS;                       // [N*H][D][L]
    bf16_t* kp = (bf16_t*)d_out;                  // staged in d_out, dead before outproj

    // Fuse the Wo convert into proj when ws has 2MB headroom past qp+vt;
    // otherwise fall back to the r13-validated separate wocvt dispatch.
    // (ws_size is fixed at graph-capture time -> host branch is capture-safe.)
    const bool fuse = ws_size >= (2 * TENS + WO_E) * sizeof(bf16_t);
    bf16_t* wo_bf = fuse ? (qp + 2 * TENS) : vt;  // vt is dead after attn

    hipLaunchKernelGGL(proj_kernel, dim3(2048, fuse ? 4 : 3), dim3(256), 0, stream,
                       query, key, value, Wq, Wk, Wv, Wo, qp, kp, vt, wo_bf);
    hipLaunchKernelGGL(attn_kernel, dim3(1024), dim3(256), 0, stream, qp, kp, vt);
    if (!fuse)
        hipLaunchKernelGGL(wocvt_kernel, dim3(512), dim3(256), 0, stream, Wo, wo_bf);
    hipLaunchKernelGGL(outproj_kernel, dim3(1024), dim3(256), 0, stream,
                       qp, wo_bf, (float*)d_out);
}